// Round 5
// baseline (602.271 us; speedup 1.0000x reference)
//
#include <hip/hip_runtime.h>
#include <hip/hip_bf16.h>
#include <math.h>

#define B_  128
#define L_  196
#define F_  2048
#define H_  512
#define A_  512
#define ML_ (B_*L_)   // 25088 rows = 196 tiles of 128 exactly

typedef _Float16 half8 __attribute__((ext_vector_type(8)));
typedef _Float16 half4v __attribute__((ext_vector_type(4)));
typedef float f32x4 __attribute__((ext_vector_type(4)));

// async 16B global->LDS (LDS dest = wave-uniform base + lane*16)
__device__ __forceinline__ void gld_lds16(const void* g, void* l) {
  __builtin_amdgcn_global_load_lds((const __attribute__((address_space(1))) void*)g,
                                   (__attribute__((address_space(3))) void*)l, 16, 0, 0);
}

// ---------------------------------------------------------------------------
// K_prep (small): 128 blocks. Wenc fp32->f16 (4 MB, 8-deep unrolled),
// dec[b][a] = b_dec+b_enc+hs·Wdec^T, zero scores.
// ---------------------------------------------------------------------------
__global__ __launch_bounds__(256) void k_prep(const float4* __restrict__ Wenc4,
                                              half4v* __restrict__ wH,
                                              const float* __restrict__ hs,
                                              const float* __restrict__ Wdec,
                                              const float* __restrict__ bdec,
                                              const float* __restrict__ benc,
                                              float* __restrict__ dec,
                                              float* __restrict__ scores) {
  const int b = blockIdx.x, t = threadIdx.x;

  {
    const int base = b * 2048 + t;
    float4 v[8];
#pragma unroll
    for (int j = 0; j < 8; j++) v[j] = Wenc4[base + j * 256];
#pragma unroll
    for (int j = 0; j < 8; j++) {
      half4v o = { (_Float16)v[j].x, (_Float16)v[j].y, (_Float16)v[j].z, (_Float16)v[j].w };
      wH[base + j * 256] = o;
    }
  }

  const int g = b * 256 + t;
  if (g < ML_) scores[g] = 0.f;

  __shared__ float h[H_];
  h[t]       = hs[b * H_ + t];
  h[t + 256] = hs[b * H_ + t + 256];
  __syncthreads();

#pragma unroll
  for (int r = 0; r < 2; r++) {
    const int a = t + r * 256;
    float acc = bdec[a] + benc[a];
    const float4* wr = (const float4*)(Wdec + (size_t)a * H_);
#pragma unroll 4
    for (int k4 = 0; k4 < H_ / 4; k4++) {
      const float4 w = wr[k4];
      acc += w.x * h[4*k4] + w.y * h[4*k4+1] + w.z * h[4*k4+2] + w.w * h[4*k4+3];
    }
    dec[b * A_ + a] = acc;
  }
}

// ---------------------------------------------------------------------------
// K2 (MFMA): scores[m] += sum_a relu(feat[m,:]·Wenc[a,:] + dec[b,a]) * wcom[a]
//   A = feat fp32 staged via global_load_lds, f16-cvt at fragment-load time.
//   B = Wenc f16. 128x128 tile, BK=32 (LDS 25 KB -> ~5-6 blocks/CU).
//   1-D grid with XCD-aware decode: the 4 a-blocks of an m-tile have linear
//   ids 8 apart (same id mod 8 -> same XCD under round-robin dispatch) so the
//   shared feat m-tile is fetched from HBM once and re-served from local L2.
//   A swizzle: row = 8 granules of 4 floats, slot = g ^ (row&7).
//   B swizzle: row = 4 granules of 8 halves, slot = g ^ (row&3).
// ---------------------------------------------------------------------------
__global__ __launch_bounds__(256, 5) void k_scores_mfma(const float* __restrict__ fA,
                                                        const _Float16* __restrict__ fB,
                                                        const float* __restrict__ dec,
                                                        const float* __restrict__ wcom,
                                                        float* __restrict__ scores) {
  __shared__ float     As[128 * 32];   // fp32, 128 B/row
  __shared__ _Float16  Bs[128 * 32];   // f16,   64 B/row
  __shared__ float decS[2][128];

  const int tid  = threadIdx.x;
  const int lane = tid & 63;
  const int w    = tid >> 6;

  // XCD-aware (mt, a-tile) decode from 1-D block id.
  const int l = blockIdx.x;
  int at_, mt;
  if (l < 768) { at_ = (l >> 3) & 3; mt = (l >> 5) * 8 + (l & 7); }
  else { const int idx = l - 768; at_ = idx >> 2; mt = 192 + (idx & 3); }
  const int a0 = at_ * 128;
  const int m0 = mt * 128;

  const int wm   = w & 1;
  const int wn   = w >> 1;
  const int quad = lane >> 4;
  const int l16  = lane & 15;

  f32x4 acc[4][4];
#pragma unroll
  for (int i = 0; i < 4; i++)
#pragma unroll
    for (int j = 0; j < 4; j++)
#pragma unroll
      for (int k = 0; k < 4; k++) acc[i][j][k] = 0.f;

  // epilogue dec rows (visibility covered by K-loop barriers)
  const int b0 = m0 / L_;
  {
    const int i = tid >> 7;
    const int j = tid & 127;
    int bb = b0 + i; if (bb > B_ - 1) bb = B_ - 1;
    decS[i][j] = dec[bb * A_ + a0 + j];
  }

  // A staging: per issue 64 lanes x 16 B = 8 rows x 8 granule-slots.
  const int srowA = lane >> 3;             // 0..7
  const int gA    = (lane & 7) ^ srowA;    // global granule fetched by this lane
  const float* pA[4];
#pragma unroll
  for (int i = 0; i < 4; i++) {
    const int rb = w * 32 + i * 8;
    pA[i] = fA + (size_t)(m0 + rb + srowA) * F_ + gA * 4;
  }
  // B staging: per issue 16 rows x 4 granule-slots.
  const int srowB = lane >> 2;             // 0..15
  const int gB    = (lane & 3) ^ (srowB & 3);
  const _Float16* pB[2];
#pragma unroll
  for (int i = 0; i < 2; i++) {
    const int rb = w * 32 + i * 16;
    pB[i] = fB + (size_t)(a0 + rb + srowB) * F_ + gB * 8;
  }

  for (int kt = 0; kt < F_; kt += 32) {
#pragma unroll
    for (int i = 0; i < 4; i++)
      gld_lds16(pA[i] + kt, &As[(w * 32 + i * 8) * 32]);
#pragma unroll
    for (int i = 0; i < 2; i++)
      gld_lds16(pB[i] + kt, &Bs[(w * 32 + i * 16) * 32]);
    __syncthreads();

    half8 af[4], bf[4];
#pragma unroll
    for (int mf = 0; mf < 4; mf++) {
      const int row = wm * 64 + mf * 16 + l16;
      const int s0  = (quad * 2) ^ (row & 7);
      const int s1  = s0 ^ 1;
      const float4 f0 = *(const float4*)&As[row * 32 + s0 * 4];
      const float4 f1 = *(const float4*)&As[row * 32 + s1 * 4];
      half8 a;
      a[0] = (_Float16)f0.x; a[1] = (_Float16)f0.y;
      a[2] = (_Float16)f0.z; a[3] = (_Float16)f0.w;
      a[4] = (_Float16)f1.x; a[5] = (_Float16)f1.y;
      a[6] = (_Float16)f1.z; a[7] = (_Float16)f1.w;
      af[mf] = a;
    }
#pragma unroll
    for (int at = 0; at < 4; at++) {
      const int row = wn * 64 + at * 16 + l16;
      const int pos = quad ^ (row & 3);
      bf[at] = *(const half8*)&Bs[row * 32 + pos * 8];
    }
#pragma unroll
    for (int mf = 0; mf < 4; mf++)
#pragma unroll
      for (int at = 0; at < 4; at++)
        acc[mf][at] = __builtin_amdgcn_mfma_f32_16x16x32_f16(af[mf], bf[at], acc[mf][at], 0, 0, 0);
    __syncthreads();
  }

  float w4[4];
#pragma unroll
  for (int at = 0; at < 4; at++) w4[at] = wcom[a0 + wn * 64 + at * 16 + l16];

#pragma unroll
  for (int mf = 0; mf < 4; mf++) {
#pragma unroll
    for (int r = 0; r < 4; r++) {
      const int m  = m0 + wm * 64 + mf * 16 + quad * 4 + r;  // C/D: row=(lane>>4)*4+reg
      const int db = m / L_ - b0;
      float p = 0.f;
#pragma unroll
      for (int at = 0; at < 4; at++) {
        const float e = acc[mf][at][r] + decS[db][wn * 64 + at * 16 + l16];
        p = fmaf(fmaxf(e, 0.f), w4[at], p);
      }
      p += __shfl_xor(p, 1);
      p += __shfl_xor(p, 2);
      p += __shfl_xor(p, 4);
      p += __shfl_xor(p, 8);
      if (l16 == 0) atomicAdd(&scores[m], p);
    }
  }
}

// ---------------------------------------------------------------------------
// K_attn: softmax(scores[b,:]) recomputed per block + weighted sum over fp32
// feat (largely LLC-warm after the GEMM stream). grid (4 f-chunks, B).
// ---------------------------------------------------------------------------
__global__ __launch_bounds__(256) void k_attn_f32(const float* __restrict__ feat,
                                                  const float* __restrict__ scores,
                                                  float* __restrict__ alpha,
                                                  float* __restrict__ out) {
  const int fc = blockIdx.x, b = blockIdx.y, t = threadIdx.x;
  __shared__ float al[L_];
  __shared__ float redm[4];
  __shared__ float reds[4];

  float s = (t < L_) ? scores[b * L_ + t] : -INFINITY;
  float m = s;
#pragma unroll
  for (int o = 32; o >= 1; o >>= 1) m = fmaxf(m, __shfl_xor(m, o));
  if ((t & 63) == 0) redm[t >> 6] = m;
  __syncthreads();
  m = fmaxf(fmaxf(redm[0], redm[1]), fmaxf(redm[2], redm[3]));
  float e = (t < L_) ? expf(s - m) : 0.f;
  float sum = e;
#pragma unroll
  for (int o = 32; o >= 1; o >>= 1) sum += __shfl_xor(sum, o);
  if ((t & 63) == 0) reds[t >> 6] = sum;
  __syncthreads();
  sum = reds[0] + reds[1] + reds[2] + reds[3];
  if (t < L_) {
    const float a = e / sum;
    al[t] = a;
    if (fc == 0) alpha[b * L_ + t] = a;
  }
  __syncthreads();

  const int f0 = fc * 512 + t * 2;
  const float2* fp = (const float2*)(feat + (size_t)b * L_ * F_ + f0);
  float ax = 0.f, ay = 0.f;
#pragma unroll 4
  for (int ll = 0; ll < L_; ll++) {
    const float2 v = fp[(size_t)ll * (F_ / 2)];
    const float wgt = al[ll];
    ax = fmaf(v.x, wgt, ax);
    ay = fmaf(v.y, wgt, ay);
  }
  float2 o = { ax, ay };
  *(float2*)(out + (size_t)b * F_ + f0) = o;
}

// ---------------------------------------------------------------------------
// Fallback fp32 GEMM path (ws too small — effectively never taken)
// ---------------------------------------------------------------------------
__global__ __launch_bounds__(256) void k_scores_f32(const float* __restrict__ feat,
                                                    const float* __restrict__ Wenc,
                                                    const float* __restrict__ dec,
                                                    const float* __restrict__ wcom,
                                                    float* __restrict__ scores) {
  __shared__ float As[16][128];
  __shared__ float Bs[16][128];
  const int tid = threadIdx.x;
  const int m0 = blockIdx.x * 128;
  const int a0 = blockIdx.y * 128;
  const int tx = tid & 15;
  const int ty = tid >> 4;
  float acc[8][8];
#pragma unroll
  for (int i = 0; i < 8; i++)
#pragma unroll
    for (int j = 0; j < 8; j++) acc[i][j] = 0.f;
  for (int kt = 0; kt < F_; kt += 16) {
#pragma unroll
    for (int rep = 0; rep < 2; rep++) {
      const int idx = rep * 256 + tid;
      const int row = idx >> 2;
      const int kp  = (idx & 3) << 2;
      const float4 v = *(const float4*)(feat + (size_t)(m0 + row) * F_ + kt + kp);
      As[kp+0][row] = v.x; As[kp+1][row] = v.y; As[kp+2][row] = v.z; As[kp+3][row] = v.w;
      const float4 w = *(const float4*)(Wenc + (size_t)(a0 + row) * F_ + kt + kp);
      Bs[kp+0][row] = w.x; Bs[kp+1][row] = w.y; Bs[kp+2][row] = w.z; Bs[kp+3][row] = w.w;
    }
    __syncthreads();
#pragma unroll
    for (int k = 0; k < 16; k++) {
      float ar[8], br[8];
      *(float4*)&ar[0] = *(const float4*)&As[k][ty * 8];
      *(float4*)&ar[4] = *(const float4*)&As[k][ty * 8 + 4];
      *(float4*)&br[0] = *(const float4*)&Bs[k][tx * 8];
      *(float4*)&br[4] = *(const float4*)&Bs[k][tx * 8 + 4];
#pragma unroll
      for (int i = 0; i < 8; i++)
#pragma unroll
        for (int j = 0; j < 8; j++) acc[i][j] = fmaf(ar[i], br[j], acc[i][j]);
    }
    __syncthreads();
  }
  float w8[8];
  *(float4*)&w8[0] = *(const float4*)(wcom + a0 + tx * 8);
  *(float4*)&w8[4] = *(const float4*)(wcom + a0 + tx * 8 + 4);
#pragma unroll
  for (int i = 0; i < 8; i++) {
    const int m = m0 + ty * 8 + i;
    const int b = m / L_;
    const float* dp = dec + b * A_ + a0 + tx * 8;
    float p = 0.f;
#pragma unroll
    for (int j = 0; j < 8; j++) {
      const float e = acc[i][j] + dp[j];
      p = fmaf(fmaxf(e, 0.f), w8[j], p);
    }
    p += __shfl_xor(p, 1);
    p += __shfl_xor(p, 2);
    p += __shfl_xor(p, 4);
    p += __shfl_xor(p, 8);
    if (tx == 0) atomicAdd(&scores[m], p);
  }
}

__global__ __launch_bounds__(256) void k_dec_only(const float* __restrict__ hs,
                                                  const float* __restrict__ Wdec,
                                                  const float* __restrict__ bdec,
                                                  const float* __restrict__ benc,
                                                  float* __restrict__ dec,
                                                  float* __restrict__ scores) {
  const int b = blockIdx.x, t = threadIdx.x;
  const int g = b * 256 + t;
  if (g < ML_) scores[g] = 0.f;
  __shared__ float h[H_];
  h[t]       = hs[b * H_ + t];
  h[t + 256] = hs[b * H_ + t + 256];
  __syncthreads();
#pragma unroll
  for (int r = 0; r < 2; r++) {
    const int a = t + r * 256;
    float acc = bdec[a] + benc[a];
    const float4* wr = (const float4*)(Wdec + (size_t)a * H_);
#pragma unroll 4
    for (int k4 = 0; k4 < H_ / 4; k4++) {
      const float4 w = wr[k4];
      acc += w.x * h[4*k4] + w.y * h[4*k4+1] + w.z * h[4*k4+2] + w.w * h[4*k4+3];
    }
    dec[b * A_ + a] = acc;
  }
}

// ---------------------------------------------------------------------------
extern "C" void kernel_launch(void* const* d_in, const int* in_sizes, int n_in,
                              void* d_out, int out_size, void* d_ws, size_t ws_size,
                              hipStream_t stream) {
  const float* feat = (const float*)d_in[0];   // [B,L,F]
  const float* hs   = (const float*)d_in[1];   // [B,H]
  const float* Wenc = (const float*)d_in[2];   // [A,F]
  const float* benc = (const float*)d_in[3];   // [A]
  const float* Wdec = (const float*)d_in[4];   // [A,H]
  const float* bdec = (const float*)d_in[5];   // [A]
  const float* wcom = (const float*)d_in[6];   // [1,A]
  // d_in[7] = b_com: softmax-invariant, unused

  float* out   = (float*)d_out;                // [B*F] weighted ++ [B*L] alpha
  float* alpha = out + B_ * F_;
  float* dec    = (float*)d_ws;                // [B*A]
  float* scores = dec + B_ * A_;               // [B*L]

  const size_t need = (size_t)(B_ * A_ + ML_) * 4 + (size_t)A_ * F_ * 2;

  if (ws_size >= need) {
    _Float16* wH = (_Float16*)(scores + ML_);  // [A_, F_] f16
    k_prep<<<dim3(128), dim3(256), 0, stream>>>(
        (const float4*)Wenc, (half4v*)wH, hs, Wdec, bdec, benc, dec, scores);
    k_scores_mfma<<<dim3(784), dim3(256), 0, stream>>>(feat, wH, dec, wcom, scores);
  } else {
    k_dec_only<<<dim3(B_), dim3(256), 0, stream>>>(hs, Wdec, bdec, benc, dec, scores);
    k_scores_f32<<<dim3(ML_ / 128, A_ / 128), dim3(256), 0, stream>>>(feat, Wenc, dec, wcom, scores);
  }
  k_attn_f32<<<dim3(4, B_), dim3(256), 0, stream>>>(feat, scores, alpha, out);
}

// Round 6
// 464.693 us; speedup vs baseline: 1.2961x; 1.2961x over previous
//
#include <hip/hip_runtime.h>
#include <hip/hip_bf16.h>
#include <math.h>

#define B_  128
#define L_  196
#define F_  2048
#define H_  512
#define A_  512
#define ML_ (B_*L_)   // 25088 rows = 196 tiles of 128 exactly

typedef _Float16 half8 __attribute__((ext_vector_type(8)));
typedef _Float16 half4v __attribute__((ext_vector_type(4)));
typedef float f32x4 __attribute__((ext_vector_type(4)));

// async 16B global->LDS (LDS dest = wave-uniform base + lane*16)
__device__ __forceinline__ void gld_lds16(const void* g, void* l) {
  __builtin_amdgcn_global_load_lds((const __attribute__((address_space(1))) void*)g,
                                   (__attribute__((address_space(3))) void*)l, 16, 0, 0);
}

// ---------------------------------------------------------------------------
// K_prep (small): 128 blocks. Wenc fp32->f16 (4 MB, 8-deep unrolled),
// dec[b][a] = b_dec+b_enc+hs·Wdec^T, zero scores.
// ---------------------------------------------------------------------------
__global__ __launch_bounds__(256) void k_prep(const float4* __restrict__ Wenc4,
                                              half4v* __restrict__ wH,
                                              const float* __restrict__ hs,
                                              const float* __restrict__ Wdec,
                                              const float* __restrict__ bdec,
                                              const float* __restrict__ benc,
                                              float* __restrict__ dec,
                                              float* __restrict__ scores) {
  const int b = blockIdx.x, t = threadIdx.x;

  {
    const int base = b * 2048 + t;
    float4 v[8];
#pragma unroll
    for (int j = 0; j < 8; j++) v[j] = Wenc4[base + j * 256];
#pragma unroll
    for (int j = 0; j < 8; j++) {
      half4v o = { (_Float16)v[j].x, (_Float16)v[j].y, (_Float16)v[j].z, (_Float16)v[j].w };
      wH[base + j * 256] = o;
    }
  }

  const int g = b * 256 + t;
  if (g < ML_) scores[g] = 0.f;

  __shared__ float h[H_];
  h[t]       = hs[b * H_ + t];
  h[t + 256] = hs[b * H_ + t + 256];
  __syncthreads();

#pragma unroll
  for (int r = 0; r < 2; r++) {
    const int a = t + r * 256;
    float acc = bdec[a] + benc[a];
    const float4* wr = (const float4*)(Wdec + (size_t)a * H_);
#pragma unroll 4
    for (int k4 = 0; k4 < H_ / 4; k4++) {
      const float4 w = wr[k4];
      acc += w.x * h[4*k4] + w.y * h[4*k4+1] + w.z * h[4*k4+2] + w.w * h[4*k4+3];
    }
    dec[b * A_ + a] = acc;
  }
}

// ---------------------------------------------------------------------------
// K2 (MFMA): scores[m] += sum_a relu(feat[m,:]·Wenc[a,:] + dec[b,a]) * wcom[a]
//   A = feat fp32 staged via global_load_lds, f16-cvt (RNE) at frag-load time.
//   B = Wenc f16. 128x128 tile, BK=32 (LDS 25.6 KB).
//   1-D grid, XCD-aware decode: 4 a-blocks of one m-tile are 8 apart in
//   linear id -> same XCD under round-robin -> feat tile served from local L2
//   (R4 measured: FETCH 407->148 MB).
//   A swizzle: 8 granules(16B)/row, slot = g ^ (row&7)   [conflict-free]
//   B swizzle: 4 granules(16B)/row, slot = g ^ ((row>>1)&3) [conflict-free:
//     an 8-lane b128 phase gets distinct (row&1, slot) -> all 32 banks]
//   NOTE: no min-waves launch bound — R4's (256,5) forced a scratch spill
//   (VGPR 48 + 333 MB scratch writes). Allocator needs ~152 regs incl. acc.
// ---------------------------------------------------------------------------
__global__ __launch_bounds__(256) void k_scores_mfma(const float* __restrict__ fA,
                                                     const _Float16* __restrict__ fB,
                                                     const float* __restrict__ dec,
                                                     const float* __restrict__ wcom,
                                                     float* __restrict__ scores) {
  __shared__ float     As[128 * 32];   // fp32, 128 B/row
  __shared__ _Float16  Bs[128 * 32];   // f16,   64 B/row
  __shared__ float decS[2][128];

  const int tid  = threadIdx.x;
  const int lane = tid & 63;
  const int w    = tid >> 6;

  // XCD-aware (m-tile, a-tile) decode from 1-D block id.
  const int l = blockIdx.x;
  int at_, mt;
  if (l < 768) { at_ = (l >> 3) & 3; mt = (l >> 5) * 8 + (l & 7); }
  else { const int idx = l - 768; at_ = idx >> 2; mt = 192 + (idx & 3); }
  const int a0 = at_ * 128;
  const int m0 = mt * 128;

  const int wm   = w & 1;
  const int wn   = w >> 1;
  const int quad = lane >> 4;
  const int l16  = lane & 15;

  f32x4 acc[4][4];
#pragma unroll
  for (int i = 0; i < 4; i++)
#pragma unroll
    for (int j = 0; j < 4; j++)
#pragma unroll
      for (int k = 0; k < 4; k++) acc[i][j][k] = 0.f;

  // epilogue dec rows (visibility covered by K-loop barriers)
  const int b0 = m0 / L_;
  {
    const int i = tid >> 7;
    const int j = tid & 127;
    int bb = b0 + i; if (bb > B_ - 1) bb = B_ - 1;
    decS[i][j] = dec[bb * A_ + a0 + j];
  }

  // A staging: per issue 64 lanes x 16 B = 8 rows x 8 granule-slots.
  const int srowA = lane >> 3;             // 0..7
  const int gA    = (lane & 7) ^ srowA;    // global granule fetched by this lane
  const float* pA[4];
#pragma unroll
  for (int i = 0; i < 4; i++) {
    const int rb = w * 32 + i * 8;
    pA[i] = fA + (size_t)(m0 + rb + srowA) * F_ + gA * 4;
  }
  // B staging: per issue 16 rows x 4 granule-slots, slot = g ^ ((row>>1)&3).
  const int srowB = lane >> 2;             // 0..15
  const int gB    = (lane & 3) ^ ((srowB >> 1) & 3);
  const _Float16* pB[2];
#pragma unroll
  for (int i = 0; i < 2; i++) {
    const int rb = w * 32 + i * 16;
    pB[i] = fB + (size_t)(a0 + rb + srowB) * F_ + gB * 8;
  }

  for (int kt = 0; kt < F_; kt += 32) {
#pragma unroll
    for (int i = 0; i < 4; i++)
      gld_lds16(pA[i] + kt, &As[(w * 32 + i * 8) * 32]);
#pragma unroll
    for (int i = 0; i < 2; i++)
      gld_lds16(pB[i] + kt, &Bs[(w * 32 + i * 16) * 32]);
    __syncthreads();

    half8 af[4], bf[4];
#pragma unroll
    for (int mf = 0; mf < 4; mf++) {
      const int row = wm * 64 + mf * 16 + l16;
      const int s0  = (quad * 2) ^ (row & 7);
      const int s1  = s0 ^ 1;
      const float4 f0 = *(const float4*)&As[row * 32 + s0 * 4];
      const float4 f1 = *(const float4*)&As[row * 32 + s1 * 4];
      half8 a;
      a[0] = (_Float16)f0.x; a[1] = (_Float16)f0.y;
      a[2] = (_Float16)f0.z; a[3] = (_Float16)f0.w;
      a[4] = (_Float16)f1.x; a[5] = (_Float16)f1.y;
      a[6] = (_Float16)f1.z; a[7] = (_Float16)f1.w;
      af[mf] = a;
    }
#pragma unroll
    for (int at = 0; at < 4; at++) {
      const int row = wn * 64 + at * 16 + l16;
      const int pos = quad ^ ((row >> 1) & 3);
      bf[at] = *(const half8*)&Bs[row * 32 + pos * 8];
    }
#pragma unroll
    for (int mf = 0; mf < 4; mf++)
#pragma unroll
      for (int at = 0; at < 4; at++)
        acc[mf][at] = __builtin_amdgcn_mfma_f32_16x16x32_f16(af[mf], bf[at], acc[mf][at], 0, 0, 0);
    __syncthreads();
  }

  float w4[4];
#pragma unroll
  for (int at = 0; at < 4; at++) w4[at] = wcom[a0 + wn * 64 + at * 16 + l16];

#pragma unroll
  for (int mf = 0; mf < 4; mf++) {
#pragma unroll
    for (int r = 0; r < 4; r++) {
      const int m  = m0 + wm * 64 + mf * 16 + quad * 4 + r;  // C/D: row=(lane>>4)*4+reg
      const int db = m / L_ - b0;
      float p = 0.f;
#pragma unroll
      for (int at = 0; at < 4; at++) {
        const float e = acc[mf][at][r] + decS[db][wn * 64 + at * 16 + l16];
        p = fmaf(fmaxf(e, 0.f), w4[at], p);
      }
      p += __shfl_xor(p, 1);
      p += __shfl_xor(p, 2);
      p += __shfl_xor(p, 4);
      p += __shfl_xor(p, 8);
      if (l16 == 0) atomicAdd(&scores[m], p);
    }
  }
}

// ---------------------------------------------------------------------------
// K_attn: softmax(scores[b,:]) recomputed per block + weighted sum over fp32
// feat. grid (4 f-chunks, B).
// ---------------------------------------------------------------------------
__global__ __launch_bounds__(256) void k_attn_f32(const float* __restrict__ feat,
                                                  const float* __restrict__ scores,
                                                  float* __restrict__ alpha,
                                                  float* __restrict__ out) {
  const int fc = blockIdx.x, b = blockIdx.y, t = threadIdx.x;
  __shared__ float al[L_];
  __shared__ float redm[4];
  __shared__ float reds[4];

  float s = (t < L_) ? scores[b * L_ + t] : -INFINITY;
  float m = s;
#pragma unroll
  for (int o = 32; o >= 1; o >>= 1) m = fmaxf(m, __shfl_xor(m, o));
  if ((t & 63) == 0) redm[t >> 6] = m;
  __syncthreads();
  m = fmaxf(fmaxf(redm[0], redm[1]), fmaxf(redm[2], redm[3]));
  float e = (t < L_) ? expf(s - m) : 0.f;
  float sum = e;
#pragma unroll
  for (int o = 32; o >= 1; o >>= 1) sum += __shfl_xor(sum, o);
  if ((t & 63) == 0) reds[t >> 6] = sum;
  __syncthreads();
  sum = reds[0] + reds[1] + reds[2] + reds[3];
  if (t < L_) {
    const float a = e / sum;
    al[t] = a;
    if (fc == 0) alpha[b * L_ + t] = a;
  }
  __syncthreads();

  const int f0 = fc * 512 + t * 2;
  const float2* fp = (const float2*)(feat + (size_t)b * L_ * F_ + f0);
  float ax = 0.f, ay = 0.f;
#pragma unroll 4
  for (int ll = 0; ll < L_; ll++) {
    const float2 v = fp[(size_t)ll * (F_ / 2)];
    const float wgt = al[ll];
    ax = fmaf(v.x, wgt, ax);
    ay = fmaf(v.y, wgt, ay);
  }
  float2 o = { ax, ay };
  *(float2*)(out + (size_t)b * F_ + f0) = o;
}

// ---------------------------------------------------------------------------
// Fallback fp32 GEMM path (ws too small — effectively never taken)
// ---------------------------------------------------------------------------
__global__ __launch_bounds__(256) void k_scores_f32(const float* __restrict__ feat,
                                                    const float* __restrict__ Wenc,
                                                    const float* __restrict__ dec,
                                                    const float* __restrict__ wcom,
                                                    float* __restrict__ scores) {
  __shared__ float As[16][128];
  __shared__ float Bs[16][128];
  const int tid = threadIdx.x;
  const int m0 = blockIdx.x * 128;
  const int a0 = blockIdx.y * 128;
  const int tx = tid & 15;
  const int ty = tid >> 4;
  float acc[8][8];
#pragma unroll
  for (int i = 0; i < 8; i++)
#pragma unroll
    for (int j = 0; j < 8; j++) acc[i][j] = 0.f;
  for (int kt = 0; kt < F_; kt += 16) {
#pragma unroll
    for (int rep = 0; rep < 2; rep++) {
      const int idx = rep * 256 + tid;
      const int row = idx >> 2;
      const int kp  = (idx & 3) << 2;
      const float4 v = *(const float4*)(feat + (size_t)(m0 + row) * F_ + kt + kp);
      As[kp+0][row] = v.x; As[kp+1][row] = v.y; As[kp+2][row] = v.z; As[kp+3][row] = v.w;
      const float4 w = *(const float4*)(Wenc + (size_t)(a0 + row) * F_ + kt + kp);
      Bs[kp+0][row] = w.x; Bs[kp+1][row] = w.y; Bs[kp+2][row] = w.z; Bs[kp+3][row] = w.w;
    }
    __syncthreads();
#pragma unroll
    for (int k = 0; k < 16; k++) {
      float ar[8], br[8];
      *(float4*)&ar[0] = *(const float4*)&As[k][ty * 8];
      *(float4*)&ar[4] = *(const float4*)&As[k][ty * 8 + 4];
      *(float4*)&br[0] = *(const float4*)&Bs[k][tx * 8];
      *(float4*)&br[4] = *(const float4*)&Bs[k][tx * 8 + 4];
#pragma unroll
      for (int i = 0; i < 8; i++)
#pragma unroll
        for (int j = 0; j < 8; j++) acc[i][j] = fmaf(ar[i], br[j], acc[i][j]);
    }
    __syncthreads();
  }
  float w8[8];
  *(float4*)&w8[0] = *(const float4*)(wcom + a0 + tx * 8);
  *(float4*)&w8[4] = *(const float4*)(wcom + a0 + tx * 8 + 4);
#pragma unroll
  for (int i = 0; i < 8; i++) {
    const int m = m0 + ty * 8 + i;
    const int b = m / L_;
    const float* dp = dec + b * A_ + a0 + tx * 8;
    float p = 0.f;
#pragma unroll
    for (int j = 0; j < 8; j++) {
      const float e = acc[i][j] + dp[j];
      p = fmaf(fmaxf(e, 0.f), w8[j], p);
    }
    p += __shfl_xor(p, 1);
    p += __shfl_xor(p, 2);
    p += __shfl_xor(p, 4);
    p += __shfl_xor(p, 8);
    if (tx == 0) atomicAdd(&scores[m], p);
  }
}

__global__ __launch_bounds__(256) void k_dec_only(const float* __restrict__ hs,
                                                  const float* __restrict__ Wdec,
                                                  const float* __restrict__ bdec,
                                                  const float* __restrict__ benc,
                                                  float* __restrict__ dec,
                                                  float* __restrict__ scores) {
  const int b = blockIdx.x, t = threadIdx.x;
  const int g = b * 256 + t;
  if (g < ML_) scores[g] = 0.f;
  __shared__ float h[H_];
  h[t]       = hs[b * H_ + t];
  h[t + 256] = hs[b * H_ + t + 256];
  __syncthreads();
#pragma unroll
  for (int r = 0; r < 2; r++) {
    const int a = t + r * 256;
    float acc = bdec[a] + benc[a];
    const float4* wr = (const float4*)(Wdec + (size_t)a * H_);
#pragma unroll 4
    for (int k4 = 0; k4 < H_ / 4; k4++) {
      const float4 w = wr[k4];
      acc += w.x * h[4*k4] + w.y * h[4*k4+1] + w.z * h[4*k4+2] + w.w * h[4*k4+3];
    }
    dec[b * A_ + a] = acc;
  }
}

// ---------------------------------------------------------------------------
extern "C" void kernel_launch(void* const* d_in, const int* in_sizes, int n_in,
                              void* d_out, int out_size, void* d_ws, size_t ws_size,
                              hipStream_t stream) {
  const float* feat = (const float*)d_in[0];   // [B,L,F]
  const float* hs   = (const float*)d_in[1];   // [B,H]
  const float* Wenc = (const float*)d_in[2];   // [A,F]
  const float* benc = (const float*)d_in[3];   // [A]
  const float* Wdec = (const float*)d_in[4];   // [A,H]
  const float* bdec = (const float*)d_in[5];   // [A]
  const float* wcom = (const float*)d_in[6];   // [1,A]
  // d_in[7] = b_com: softmax-invariant, unused

  float* out   = (float*)d_out;                // [B*F] weighted ++ [B*L] alpha
  float* alpha = out + B_ * F_;
  float* dec    = (float*)d_ws;                // [B*A]
  float* scores = dec + B_ * A_;               // [B*L]

  const size_t need = (size_t)(B_ * A_ + ML_) * 4 + (size_t)A_ * F_ * 2;

  if (ws_size >= need) {
    _Float16* wH = (_Float16*)(scores + ML_);  // [A_, F_] f16
    k_prep<<<dim3(128), dim3(256), 0, stream>>>(
        (const float4*)Wenc, (half4v*)wH, hs, Wdec, bdec, benc, dec, scores);
    k_scores_mfma<<<dim3(784), dim3(256), 0, stream>>>(feat, wH, dec, wcom, scores);
  } else {
    k_dec_only<<<dim3(B_), dim3(256), 0, stream>>>(hs, Wdec, bdec, benc, dec, scores);
    k_scores_f32<<<dim3(ML_ / 128, A_ / 128), dim3(256), 0, stream>>>(feat, Wenc, dec, wcom, scores);
  }
  k_attn_f32<<<dim3(4, B_), dim3(256), 0, stream>>>(feat, scores, alpha, out);
}